// Round 5
// baseline (5993.689 us; speedup 1.0000x reference)
//
#include <hip/hip_runtime.h>
#include <hip/hip_bf16.h>

#define NPTS 8192
#define DIM 32
#define KKDE 32
#define KRIPS 16
#define DESTNUM 10

__device__ __forceinline__ unsigned long long shfl_xor_u64(unsigned long long v, int m) {
  int lo = __shfl_xor((int)(unsigned)(v & 0xFFFFFFFFull), m, 64);
  int hi = __shfl_xor((int)(unsigned)(v >> 32), m, 64);
  return (((unsigned long long)(unsigned)hi) << 32) | (unsigned)lo;
}

// ---------------- dtype detector: is x bf16-packed or f32? ----------------
// Sample 64 EVEN u16 words. bf16 storage: word = a bf16 value, exponent field
// clustered in [110,130] for N(0,1) samples (~99% hit). f32 storage: even words
// are low mantissa halves -> uniform bits (~8% hit). Flag = 1 iff bf16.
__global__ __launch_bounds__(64) void detect_kernel(const unsigned short* __restrict__ x,
                                                    int* __restrict__ flag) {
  int lane = threadIdx.x;
  unsigned u = x[2 * lane];
  int e = (u >> 7) & 0xFF;
  bool pass = (e >= 110 && e <= 130);
  unsigned long long b = __ballot(pass);
  if (lane == 0) flag[0] = (__popcll(b) >= 32) ? 1 : 0;
}

// ---------------- kNN: kde (32-NN) + rips indices (16-NN) ----------------
// one block per row i; dtype-adaptive x loads; fused sq; full d2 row in LDS;
// 32x argmin extraction. sqi/dot/sqj share one sequential fma chain so the
// diagonal cancels to exactly 0 in both dtype paths.
__global__ __launch_bounds__(256) void knn_kernel(const unsigned short* __restrict__ xh,
                                                  const int* __restrict__ flag,
                                                  float* __restrict__ kde,
                                                  int* __restrict__ rips) {
  __shared__ float row[NPTS];                 // 32 KB
  __shared__ unsigned long long wred[4];
  __shared__ float knnv[KKDE];
  __shared__ int knni[KKDE];
  __shared__ float xis[DIM];
  __shared__ int flagS;
  const int i = blockIdx.x;
  const int t = threadIdx.x;
  if (t == 0) flagS = flag[0];
  __syncthreads();
  const bool isbf16 = (flagS != 0);
  const float* xf = (const float*)xh;
  if (t < DIM)
    xis[t] = isbf16 ? __uint_as_float(((unsigned)xh[i * DIM + t]) << 16)
                    : xf[i * DIM + t];
  __syncthreads();
  float xi[DIM];
#pragma unroll
  for (int q = 0; q < DIM; ++q) xi[q] = xis[q];
  float sqi = 0.f;
#pragma unroll
  for (int q = 0; q < DIM; ++q) sqi = fmaf(xi[q], xi[q], sqi);
  for (int j = t; j < NPTS; j += 256) {
    float xr[DIM];
    if (isbf16) {
      const uint4* xj = (const uint4*)(xh + j * DIM);  // 4 x uint4 = 32 bf16
#pragma unroll
      for (int q = 0; q < DIM / 8; ++q) {
        uint4 w = xj[q];
        xr[q * 8 + 0] = __uint_as_float(w.x << 16);
        xr[q * 8 + 1] = __uint_as_float(w.x & 0xFFFF0000u);
        xr[q * 8 + 2] = __uint_as_float(w.y << 16);
        xr[q * 8 + 3] = __uint_as_float(w.y & 0xFFFF0000u);
        xr[q * 8 + 4] = __uint_as_float(w.z << 16);
        xr[q * 8 + 5] = __uint_as_float(w.z & 0xFFFF0000u);
        xr[q * 8 + 6] = __uint_as_float(w.w << 16);
        xr[q * 8 + 7] = __uint_as_float(w.w & 0xFFFF0000u);
      }
    } else {
      const float4* xj = (const float4*)(xf + j * DIM);  // 8 x float4 = 32 f32
#pragma unroll
      for (int q = 0; q < DIM / 4; ++q) {
        float4 w = xj[q];
        xr[q * 4 + 0] = w.x;
        xr[q * 4 + 1] = w.y;
        xr[q * 4 + 2] = w.z;
        xr[q * 4 + 3] = w.w;
      }
    }
    float dot = 0.f, sqj = 0.f;
#pragma unroll
    for (int q = 0; q < DIM; ++q) {
      dot = fmaf(xi[q], xr[q], dot);
      sqj = fmaf(xr[q], xr[q], sqj);
    }
    // j==i: dot==sqi==sqj bitwise (identical chains) -> fmaf(-2,s,2s) == 0 exactly
    row[j] = fmaxf(fmaf(-2.f, dot, sqi + sqj), 0.f);
  }
  __syncthreads();
  for (int k = 0; k < KKDE; ++k) {
    unsigned long long best = ~0ull;  // key = (f32 bits << 32) | idx: min => (min d2, min idx)
    for (int j = t; j < NPTS; j += 256) {
      unsigned long long kk = (((unsigned long long)__float_as_uint(row[j])) << 32) | (unsigned)j;
      if (kk < best) best = kk;
    }
#pragma unroll
    for (int m = 32; m; m >>= 1) {
      unsigned long long o = shfl_xor_u64(best, m);
      if (o < best) best = o;
    }
    if ((t & 63) == 0) wred[t >> 6] = best;
    __syncthreads();
    if (t == 0) {
      best = wred[0];
      if (wred[1] < best) best = wred[1];
      if (wred[2] < best) best = wred[2];
      if (wred[3] < best) best = wred[3];
      int bi = (int)(best & 0xFFFFFFFFull);
      knnv[k] = __uint_as_float((unsigned)(best >> 32));
      knni[k] = bi;
      row[bi] = __uint_as_float(0x7F800000u);  // +inf: remove from further mins
    }
    __syncthreads();
  }
  if (t == 0) {
    float s = 0.f;
    for (int k = 0; k < KKDE; ++k) s += expf(knnv[k] * -0.015625f);  // exp(-d2/64), ascending d2
    kde[i] = s;
  }
  if (t < KRIPS) rips[i * KRIPS + t] = knni[t];
}

// ---------------- max(kde) ----------------
__global__ __launch_bounds__(256) void max_kernel(const float* __restrict__ kde,
                                                  float* __restrict__ scalf) {
  __shared__ float red[256];
  int t = threadIdx.x;
  float m = 0.f;
  for (int p = t; p < NPTS; p += 256) m = fmaxf(m, kde[p]);
  red[t] = m;
  __syncthreads();
  for (int s = 128; s; s >>= 1) {
    if (t < s) red[t] = fmaxf(red[t], red[t + s]);
    __syncthreads();
  }
  if (t == 0) scalf[0] = red[0];
}

// ---------------- normalize + init death ----------------
__global__ __launch_bounds__(256) void norm_kernel(float* __restrict__ kde,
                                                   const float* __restrict__ scalf,
                                                   int* __restrict__ death) {
  int p = blockIdx.x * 256 + threadIdx.x;
  if (p < NPTS) {
    kde[p] = kde[p] / scalf[0];
    death[p] = -1;
  }
}

// ---------------- argmin(kde) (first-index ties, like jnp.argmin) ----------------
__global__ __launch_bounds__(256) void argmin_kernel(const float* __restrict__ kde,
                                                     int* __restrict__ scali) {
  __shared__ unsigned long long red[256];
  int t = threadIdx.x;
  unsigned long long best = ~0ull;
  for (int p = t; p < NPTS; p += 256) {
    unsigned long long kk = (((unsigned long long)__float_as_uint(kde[p])) << 32) | (unsigned)p;
    if (kk < best) best = kk;
  }
  red[t] = best;
  __syncthreads();
  for (int s = 128; s; s >>= 1) {
    if (t < s && red[t + s] < red[t]) red[t] = red[t + s];
    __syncthreads();
  }
  if (t == 0) scali[0] = (int)(red[0] & 0xFFFFFFFFull);
}

// ---------------- bitonic sort: order = argsort(-kde) (stable), rank = inverse ----------------
// 48 KB LDS (f32 keys + u16 indices)
__global__ __launch_bounds__(256) void sort_kernel(const float* __restrict__ kde,
                                                   int* __restrict__ order,
                                                   int* __restrict__ rankp) {
  __shared__ float kv[NPTS];            // 32 KB
  __shared__ unsigned short ki[NPTS];   // 16 KB
  int t = threadIdx.x;
  for (int p = t; p < NPTS; p += 256) { kv[p] = kde[p]; ki[p] = (unsigned short)p; }
  __syncthreads();
  for (int size = 2; size <= NPTS; size <<= 1) {
    for (int stride = size >> 1; stride > 0; stride >>= 1) {
      for (int q = t; q < NPTS / 2; q += 256) {
        int lo = ((q & ~(stride - 1)) << 1) | (q & (stride - 1));
        int hi = lo + stride;
        float va = kv[lo], vb = kv[hi];
        int ia = ki[lo], ib = ki[hi];
        // "a first" = descending kde, ties -> lower index (stable argsort of -kde)
        bool aFirst = (va > vb) || (va == vb && ia < ib);
        bool up = ((lo & size) == 0);
        if (up != aFirst) {
          kv[lo] = vb; kv[hi] = va;
          ki[lo] = (unsigned short)ib; ki[hi] = (unsigned short)ia;
        }
      }
      __syncthreads();
    }
  }
  for (int p = t; p < NPTS; p += 256) {
    int idx = ki[p];
    order[p] = idx;
    rankp[idx] = p;
  }
}

// ---------------- build ordered neighbor stream with validity bit ----------------
__global__ __launch_bounds__(256) void onbr_kernel(const int* __restrict__ order,
                                                   const int* __restrict__ rankp,
                                                   const int* __restrict__ rips,
                                                   unsigned short* __restrict__ onbr) {
  int e = blockIdx.x * 256 + threadIdx.x;  // e < NPTS*KRIPS
  if (e >= NPTS * KRIPS) return;
  int t = e >> 4, kk = e & 15;
  int i = order[t];
  int nbr = rips[i * KRIPS + kk];
  bool valid = rankp[nbr] < t;  // self has rank == t -> invalid, matching ref
  onbr[e] = (unsigned short)(nbr | (valid ? 0x8000 : 0));
}

// ---------------- sequential persistence scan (union-find, elder rule) ----------------
// Single wave. par[p] = parent (u16), root <=> par[p]==p. 48 KB LDS total.
__global__ __launch_bounds__(64) void scan_kernel(const float* __restrict__ kde,
                                                  const int* __restrict__ order,
                                                  const unsigned short* __restrict__ onbr,
                                                  int* __restrict__ death,
                                                  const int* __restrict__ scali) {
  __shared__ float kdeS[NPTS];          // 32 KB
  __shared__ unsigned short par[NPTS];  // 16 KB
  const int lane = threadIdx.x;
  for (int p = lane; p < NPTS; p += 64) { kdeS[p] = kde[p]; par[p] = (unsigned short)p; }
  __syncthreads();
  const int kk = lane & 15;
  unsigned short curD = onbr[lane];
  int curI = order[lane & 3];
  const int NG = NPTS / 4;
  for (int grp = 0; grp < NG; ++grp) {
    unsigned short nxtD = 0;
    int nxtI = 0;
    if (grp + 1 < NG) {
      nxtD = onbr[(grp + 1) * 64 + lane];
      nxtI = order[(grp + 1) * 4 + (lane & 3)];
    }
    for (int s = 0; s < 4; ++s) {
      int di = __shfl((int)curD, s * 16 + kk, 64);
      int i = __shfl(curI, s, 64);
      int nbr = di & 0x1FFF;
      bool valid = (di & 0x8000) != 0;
      // find root, uncapped, pointer-halving compression (same-wave LDS ops ordered)
      int r = nbr;
      int prev = -1;
      while (true) {
        int pp = par[r];
        if (__all(pp == r)) break;
        if (lane < 16 && prev >= 0) par[prev] = (unsigned short)pp;
        prev = r;
        r = pp;
      }
      if (lane < 16 && valid && nbr != r) par[nbr] = (unsigned short)r;
      // elder-rule argmax over k (first-occurrence tie-break == jnp.argmax)
      float kr = valid ? kdeS[r] : -1.0f;
      float m = kr;
#pragma unroll
      for (int mk = 1; mk <= 8; mk <<= 1) m = fmaxf(m, __shfl_xor(m, mk, 64));
      int g;
      if (m < 0.f) {
        g = i;  // no valid neighbors
      } else {
        unsigned long long b = __ballot(valid && kr == m) & 0xFFFFull;
        int kwin = __ffsll(b) - 1;
        g = __shfl(r, kwin, 64);
      }
      bool dying = (lane < 16) && valid && (r != g);
      if (dying) {
        par[r] = (unsigned short)g;
        death[r] = i;
      }
      if (lane == 0) par[i] = (unsigned short)g;
      __syncthreads();
    }
    curD = nxtD;
    curI = nxtI;
  }
  if (lane == 0) death[order[0]] = scali[0];  // essential pair
}

// ---------------- loss: top-10 persistence, l_change + l_salient (f32 out) ----------------
__global__ __launch_bounds__(256) void loss_kernel(const float* __restrict__ kde,
                                                   const int* __restrict__ death,
                                                   float* __restrict__ out) {
  __shared__ float redv[256];
  __shared__ int redi[256];
  const int t = threadIdx.x;
  int chosen[DESTNUM];
  for (int k = 0; k < DESTNUM; ++k) {
    float bv = -__builtin_inff();
    int bi = 1 << 30;
    for (int p = t; p < NPTS; p += 256) {
      int d = death[p];
      if (d < 0) continue;
      bool used = false;
      for (int c = 0; c < k; ++c) used |= (chosen[c] == p);
      if (used) continue;
      float pers = kde[p] - kde[d];
      if (pers > bv || (pers == bv && p < bi)) { bv = pers; bi = p; }
    }
    redv[t] = bv; redi[t] = bi;
    __syncthreads();
    for (int s = 128; s; s >>= 1) {
      if (t < s) {
        if (redv[t + s] > redv[t] || (redv[t + s] == redv[t] && redi[t + s] < redi[t])) {
          redv[t] = redv[t + s];
          redi[t] = redi[t + s];
        }
      }
      __syncthreads();
    }
    chosen[k] = redi[0];
    __syncthreads();
  }
  float acc = 0.f;
  for (int p = t; p < NPTS; p += 256) {
    int d = death[p];
    if (d < 0) continue;
    bool sal = false;
    for (int c = 0; c < DESTNUM; ++c) sal |= (chosen[c] == p);
    float dv = kde[d];
    float kp = kde[p];
    acc += sal ? ((kp - 1.f) * (kp - 1.f) + dv * dv) : (kp - dv) * (kp - dv);
  }
  redv[t] = acc;
  __syncthreads();
  for (int s = 128; s; s >>= 1) {
    if (t < s) redv[t] += redv[t + s];
    __syncthreads();
  }
  if (t == 0) out[0] = redv[0];
}

extern "C" void kernel_launch(void* const* d_in, const int* in_sizes, int n_in,
                              void* d_out, int out_size, void* d_ws, size_t ws_size,
                              hipStream_t stream) {
  const unsigned short* x = (const unsigned short*)d_in[0];

  float* kde = (float*)d_ws;                      // NPTS f32
  float* scalf = kde + NPTS;                      // [0] = kdemax
  int* scali = (int*)(scalf + 64);                // [0] = argmin idx
  int* flag = scali + 64;                         // [0] = dtype flag (1=bf16, 0=f32)
  int* order = flag + 64;                         // NPTS
  int* rankp = order + NPTS;                      // NPTS
  int* rips = rankp + NPTS;                       // NPTS*KRIPS
  unsigned short* onbr = (unsigned short*)(rips + NPTS * KRIPS);  // NPTS*KRIPS u16
  int* death = (int*)(onbr + NPTS * KRIPS);       // NPTS

  hipLaunchKernelGGL(detect_kernel, dim3(1), dim3(64), 0, stream, x, flag);
  hipLaunchKernelGGL(knn_kernel, dim3(NPTS), dim3(256), 0, stream, x, flag, kde, rips);
  hipLaunchKernelGGL(max_kernel, dim3(1), dim3(256), 0, stream, kde, scalf);
  hipLaunchKernelGGL(norm_kernel, dim3(NPTS / 256), dim3(256), 0, stream, kde, scalf, death);
  hipLaunchKernelGGL(argmin_kernel, dim3(1), dim3(256), 0, stream, kde, scali);
  hipLaunchKernelGGL(sort_kernel, dim3(1), dim3(256), 0, stream, kde, order, rankp);
  hipLaunchKernelGGL(onbr_kernel, dim3(NPTS * KRIPS / 256), dim3(256), 0, stream,
                     order, rankp, rips, onbr);
  hipLaunchKernelGGL(scan_kernel, dim3(1), dim3(64), 0, stream, kde, order, onbr, death, scali);
  hipLaunchKernelGGL(loss_kernel, dim3(1), dim3(256), 0, stream, kde, death, (float*)d_out);
}

// Round 6
// 4666.067 us; speedup vs baseline: 1.2845x; 1.2845x over previous
//
#include <hip/hip_runtime.h>
#include <hip/hip_bf16.h>

#define NPTS 8192
#define DIM 32
#define KKDE 32
#define KRIPS 16
#define DESTNUM 10

__device__ __forceinline__ unsigned long long shfl_xor_u64(unsigned long long v, int m) {
  int lo = __shfl_xor((int)(unsigned)(v & 0xFFFFFFFFull), m, 64);
  int hi = __shfl_xor((int)(unsigned)(v >> 32), m, 64);
  return (((unsigned long long)(unsigned)hi) << 32) | (unsigned)lo;
}

// ---------------- dtype detector: is x bf16-packed or f32? ----------------
__global__ __launch_bounds__(64) void detect_kernel(const unsigned short* __restrict__ x,
                                                    int* __restrict__ flag) {
  int lane = threadIdx.x;
  unsigned u = x[2 * lane];
  int e = (u >> 7) & 0xFF;
  bool pass = (e >= 110 && e <= 130);
  unsigned long long b = __ballot(pass);
  if (lane == 0) flag[0] = (__popcll(b) >= 32) ? 1 : 0;
}

// ---------------- kNN: kde (32-NN) + rips indices (16-NN) ----------------
__global__ __launch_bounds__(256) void knn_kernel(const unsigned short* __restrict__ xh,
                                                  const int* __restrict__ flag,
                                                  float* __restrict__ kde,
                                                  int* __restrict__ rips) {
  __shared__ float row[NPTS];                 // 32 KB
  __shared__ unsigned long long wred[4];
  __shared__ float knnv[KKDE];
  __shared__ int knni[KKDE];
  __shared__ float xis[DIM];
  __shared__ int flagS;
  const int i = blockIdx.x;
  const int t = threadIdx.x;
  if (t == 0) flagS = flag[0];
  __syncthreads();
  const bool isbf16 = (flagS != 0);
  const float* xf = (const float*)xh;
  if (t < DIM)
    xis[t] = isbf16 ? __uint_as_float(((unsigned)xh[i * DIM + t]) << 16)
                    : xf[i * DIM + t];
  __syncthreads();
  float xi[DIM];
#pragma unroll
  for (int q = 0; q < DIM; ++q) xi[q] = xis[q];
  float sqi = 0.f;
#pragma unroll
  for (int q = 0; q < DIM; ++q) sqi = fmaf(xi[q], xi[q], sqi);
  for (int j = t; j < NPTS; j += 256) {
    float xr[DIM];
    if (isbf16) {
      const uint4* xj = (const uint4*)(xh + j * DIM);
#pragma unroll
      for (int q = 0; q < DIM / 8; ++q) {
        uint4 w = xj[q];
        xr[q * 8 + 0] = __uint_as_float(w.x << 16);
        xr[q * 8 + 1] = __uint_as_float(w.x & 0xFFFF0000u);
        xr[q * 8 + 2] = __uint_as_float(w.y << 16);
        xr[q * 8 + 3] = __uint_as_float(w.y & 0xFFFF0000u);
        xr[q * 8 + 4] = __uint_as_float(w.z << 16);
        xr[q * 8 + 5] = __uint_as_float(w.z & 0xFFFF0000u);
        xr[q * 8 + 6] = __uint_as_float(w.w << 16);
        xr[q * 8 + 7] = __uint_as_float(w.w & 0xFFFF0000u);
      }
    } else {
      const float4* xj = (const float4*)(xf + j * DIM);
#pragma unroll
      for (int q = 0; q < DIM / 4; ++q) {
        float4 w = xj[q];
        xr[q * 4 + 0] = w.x;
        xr[q * 4 + 1] = w.y;
        xr[q * 4 + 2] = w.z;
        xr[q * 4 + 3] = w.w;
      }
    }
    float dot = 0.f, sqj = 0.f;
#pragma unroll
    for (int q = 0; q < DIM; ++q) {
      dot = fmaf(xi[q], xr[q], dot);
      sqj = fmaf(xr[q], xr[q], sqj);
    }
    // j==i: dot==sqi==sqj bitwise (identical chains) -> fmaf(-2,s,2s) == 0 exactly
    row[j] = fmaxf(fmaf(-2.f, dot, sqi + sqj), 0.f);
  }
  __syncthreads();
  for (int k = 0; k < KKDE; ++k) {
    unsigned long long best = ~0ull;  // key = (f32 bits << 32) | idx
    for (int j = t; j < NPTS; j += 256) {
      unsigned long long kk = (((unsigned long long)__float_as_uint(row[j])) << 32) | (unsigned)j;
      if (kk < best) best = kk;
    }
#pragma unroll
    for (int m = 32; m; m >>= 1) {
      unsigned long long o = shfl_xor_u64(best, m);
      if (o < best) best = o;
    }
    if ((t & 63) == 0) wred[t >> 6] = best;
    __syncthreads();
    if (t == 0) {
      best = wred[0];
      if (wred[1] < best) best = wred[1];
      if (wred[2] < best) best = wred[2];
      if (wred[3] < best) best = wred[3];
      int bi = (int)(best & 0xFFFFFFFFull);
      knnv[k] = __uint_as_float((unsigned)(best >> 32));
      knni[k] = bi;
      row[bi] = __uint_as_float(0x7F800000u);
    }
    __syncthreads();
  }
  if (t == 0) {
    float s = 0.f;
    for (int k = 0; k < KKDE; ++k) s += expf(knnv[k] * -0.015625f);  // exp(-d2/64)
    kde[i] = s;
  }
  if (t < KRIPS) rips[i * KRIPS + t] = knni[t];
}

// ---------------- max(kde) ----------------
__global__ __launch_bounds__(256) void max_kernel(const float* __restrict__ kde,
                                                  float* __restrict__ scalf) {
  __shared__ float red[256];
  int t = threadIdx.x;
  float m = 0.f;
  for (int p = t; p < NPTS; p += 256) m = fmaxf(m, kde[p]);
  red[t] = m;
  __syncthreads();
  for (int s = 128; s; s >>= 1) {
    if (t < s) red[t] = fmaxf(red[t], red[t + s]);
    __syncthreads();
  }
  if (t == 0) scalf[0] = red[0];
}

// ---------------- normalize + init death ----------------
__global__ __launch_bounds__(256) void norm_kernel(float* __restrict__ kde,
                                                   const float* __restrict__ scalf,
                                                   int* __restrict__ death) {
  int p = blockIdx.x * 256 + threadIdx.x;
  if (p < NPTS) {
    kde[p] = kde[p] / scalf[0];
    death[p] = -1;
  }
}

// ---------------- argmin(kde) ----------------
__global__ __launch_bounds__(256) void argmin_kernel(const float* __restrict__ kde,
                                                     int* __restrict__ scali) {
  __shared__ unsigned long long red[256];
  int t = threadIdx.x;
  unsigned long long best = ~0ull;
  for (int p = t; p < NPTS; p += 256) {
    unsigned long long kk = (((unsigned long long)__float_as_uint(kde[p])) << 32) | (unsigned)p;
    if (kk < best) best = kk;
  }
  red[t] = best;
  __syncthreads();
  for (int s = 128; s; s >>= 1) {
    if (t < s && red[t + s] < red[t]) red[t] = red[t + s];
    __syncthreads();
  }
  if (t == 0) scali[0] = (int)(red[0] & 0xFFFFFFFFull);
}

// ---------------- bitonic sort: order = argsort(-kde) (stable), rank = inverse ----------------
__global__ __launch_bounds__(256) void sort_kernel(const float* __restrict__ kde,
                                                   int* __restrict__ order,
                                                   int* __restrict__ rankp) {
  __shared__ float kv[NPTS];            // 32 KB
  __shared__ unsigned short ki[NPTS];   // 16 KB
  int t = threadIdx.x;
  for (int p = t; p < NPTS; p += 256) { kv[p] = kde[p]; ki[p] = (unsigned short)p; }
  __syncthreads();
  for (int size = 2; size <= NPTS; size <<= 1) {
    for (int stride = size >> 1; stride > 0; stride >>= 1) {
      for (int q = t; q < NPTS / 2; q += 256) {
        int lo = ((q & ~(stride - 1)) << 1) | (q & (stride - 1));
        int hi = lo + stride;
        float va = kv[lo], vb = kv[hi];
        int ia = ki[lo], ib = ki[hi];
        bool aFirst = (va > vb) || (va == vb && ia < ib);
        bool up = ((lo & size) == 0);
        if (up != aFirst) {
          kv[lo] = vb; kv[hi] = va;
          ki[lo] = (unsigned short)ib; ki[hi] = (unsigned short)ia;
        }
      }
      __syncthreads();
    }
  }
  for (int p = t; p < NPTS; p += 256) {
    int idx = ki[p];
    order[p] = idx;
    rankp[idx] = p;
  }
}

// ---------------- ordered neighbor stream, TRANSPOSED group layout ----------------
// step t = grp*4+s, neighbor kk: stored at u16 index ((grp*16+kk)*4 + s), so one
// u64 load per lane per group yields that kk's descriptors for all 4 steps.
__global__ __launch_bounds__(256) void onbr_kernel(const int* __restrict__ order,
                                                   const int* __restrict__ rankp,
                                                   const int* __restrict__ rips,
                                                   unsigned short* __restrict__ onbrT) {
  int e = blockIdx.x * 256 + threadIdx.x;  // e < NPTS*KRIPS
  if (e >= NPTS * KRIPS) return;
  int t = e >> 4, kk = e & 15;
  int i = order[t];
  int nbr = rips[i * KRIPS + kk];
  bool valid = rankp[nbr] < t;  // self has rank == t -> invalid, matching ref
  int grp = t >> 2, s = t & 3;
  onbrT[((grp * 16 + kk) << 2) | s] = (unsigned short)(nbr | (valid ? 0x8000 : 0));
}

// ---------------- sequential persistence scan (union-find, elder rule) ----------------
// Single wave, 48 KB LDS. Fast path: if all valid neighbor roots are equal (the
// ~97% case on this data), g is that root, no deaths -> skip the argmax machinery.
// Slow path is the round-5 code verbatim (absmax 0.0 proven). No per-step barrier:
// one wave, LDS ops complete in issue order, par[] accesses alias-opaque to compiler.
__global__ __launch_bounds__(64) void scan_kernel(const float* __restrict__ kde,
                                                  const int* __restrict__ order,
                                                  const unsigned long long* __restrict__ onbrT,
                                                  int* __restrict__ death,
                                                  const int* __restrict__ scali) {
  __shared__ float kdeS[NPTS];          // 32 KB
  __shared__ unsigned short par[NPTS];  // 16 KB
  const int lane = threadIdx.x;
  for (int p = lane; p < NPTS; p += 64) { kdeS[p] = kde[p]; par[p] = (unsigned short)p; }
  __syncthreads();
  const int kk = lane & 15;
  unsigned long long curD = onbrT[kk];          // grp 0, this lane's kk, steps 0..3
  int curI = order[lane & 3];
  const int NG = NPTS / 4;
  for (int grp = 0; grp < NG; ++grp) {
    unsigned long long nxtD = 0;
    int nxtI = 0;
    if (grp + 1 < NG) {
      nxtD = onbrT[(grp + 1) * 16 + kk];
      nxtI = order[(grp + 1) * 4 + (lane & 3)];
    }
    for (int s = 0; s < 4; ++s) {
      int i = __shfl(curI, s, 64);              // independent -> overlaps the find
      int di = (int)((curD >> (16 * s)) & 0xFFFFull);
      int nbr = di & 0x1FFF;
      bool valid = (di & 0x8000) != 0;
      // find root, uncapped, pointer-halving compression
      int r = nbr;
      int prev = -1;
      while (true) {
        int pp = par[r];
        if (__all(pp == r)) break;
        if (lane < 16 && prev >= 0) par[prev] = (unsigned short)pp;
        prev = r;
        r = pp;
      }
      if (lane < 16 && valid && nbr != r) par[nbr] = (unsigned short)r;
      unsigned long long vb = __ballot(valid) & 0xFFFFull;
      if (vb == 0) {
        // g = i; par[i] == i already -> nothing to do, no deaths
      } else {
        int cl = __ffsll(vb) - 1;                         // uniform (SGPR)
        int gc = __builtin_amdgcn_readlane(r, cl);        // cheap uniform broadcast
        if (__all(!valid || r == gc)) {
          // all valid roots identical -> g = gc, no deaths
          if (lane == 0) par[i] = (unsigned short)gc;
        } else {
          // slow path: elder-rule argmax (first-occurrence tie-break == jnp.argmax)
          float kr = valid ? kdeS[r] : -1.0f;
          float m = kr;
#pragma unroll
          for (int mk = 1; mk <= 8; mk <<= 1) m = fmaxf(m, __shfl_xor(m, mk, 64));
          unsigned long long b = __ballot(valid && kr == m) & 0xFFFFull;
          int kwin = __ffsll(b) - 1;
          int g = __shfl(r, kwin, 64);
          bool dying = (lane < 16) && valid && (r != g);
          if (dying) {
            par[r] = (unsigned short)g;
            death[r] = i;
          }
          if (lane == 0) par[i] = (unsigned short)g;
        }
      }
    }
    curD = nxtD;
    curI = nxtI;
  }
  if (lane == 0) death[order[0]] = scali[0];  // essential pair
}

// ---------------- loss: top-10 persistence, l_change + l_salient (f32 out) ----------------
__global__ __launch_bounds__(256) void loss_kernel(const float* __restrict__ kde,
                                                   const int* __restrict__ death,
                                                   float* __restrict__ out) {
  __shared__ float redv[256];
  __shared__ int redi[256];
  const int t = threadIdx.x;
  int chosen[DESTNUM];
  for (int k = 0; k < DESTNUM; ++k) {
    float bv = -__builtin_inff();
    int bi = 1 << 30;
    for (int p = t; p < NPTS; p += 256) {
      int d = death[p];
      if (d < 0) continue;
      bool used = false;
      for (int c = 0; c < k; ++c) used |= (chosen[c] == p);
      if (used) continue;
      float pers = kde[p] - kde[d];
      if (pers > bv || (pers == bv && p < bi)) { bv = pers; bi = p; }
    }
    redv[t] = bv; redi[t] = bi;
    __syncthreads();
    for (int s = 128; s; s >>= 1) {
      if (t < s) {
        if (redv[t + s] > redv[t] || (redv[t + s] == redv[t] && redi[t + s] < redi[t])) {
          redv[t] = redv[t + s];
          redi[t] = redi[t + s];
        }
      }
      __syncthreads();
    }
    chosen[k] = redi[0];
    __syncthreads();
  }
  float acc = 0.f;
  for (int p = t; p < NPTS; p += 256) {
    int d = death[p];
    if (d < 0) continue;
    bool sal = false;
    for (int c = 0; c < DESTNUM; ++c) sal |= (chosen[c] == p);
    float dv = kde[d];
    float kp = kde[p];
    acc += sal ? ((kp - 1.f) * (kp - 1.f) + dv * dv) : (kp - dv) * (kp - dv);
  }
  redv[t] = acc;
  __syncthreads();
  for (int s = 128; s; s >>= 1) {
    if (t < s) redv[t] += redv[t + s];
    __syncthreads();
  }
  if (t == 0) out[0] = redv[0];
}

extern "C" void kernel_launch(void* const* d_in, const int* in_sizes, int n_in,
                              void* d_out, int out_size, void* d_ws, size_t ws_size,
                              hipStream_t stream) {
  const unsigned short* x = (const unsigned short*)d_in[0];

  float* kde = (float*)d_ws;                      // NPTS f32
  float* scalf = kde + NPTS;                      // [0] = kdemax
  int* scali = (int*)(scalf + 64);                // [0] = argmin idx
  int* flag = scali + 64;                         // [0] = dtype flag (1=bf16, 0=f32)
  int* order = flag + 64;                         // NPTS
  int* rankp = order + NPTS;                      // NPTS
  int* rips = rankp + NPTS;                       // NPTS*KRIPS
  unsigned short* onbrT = (unsigned short*)(rips + NPTS * KRIPS);  // NPTS*KRIPS u16 (8B-aligned)
  int* death = (int*)(onbrT + NPTS * KRIPS);      // NPTS

  hipLaunchKernelGGL(detect_kernel, dim3(1), dim3(64), 0, stream, x, flag);
  hipLaunchKernelGGL(knn_kernel, dim3(NPTS), dim3(256), 0, stream, x, flag, kde, rips);
  hipLaunchKernelGGL(max_kernel, dim3(1), dim3(256), 0, stream, kde, scalf);
  hipLaunchKernelGGL(norm_kernel, dim3(NPTS / 256), dim3(256), 0, stream, kde, scalf, death);
  hipLaunchKernelGGL(argmin_kernel, dim3(1), dim3(256), 0, stream, kde, scali);
  hipLaunchKernelGGL(sort_kernel, dim3(1), dim3(256), 0, stream, kde, order, rankp);
  hipLaunchKernelGGL(onbr_kernel, dim3(NPTS * KRIPS / 256), dim3(256), 0, stream,
                     order, rankp, rips, onbrT);
  hipLaunchKernelGGL(scan_kernel, dim3(1), dim3(64), 0, stream, kde, order,
                     (const unsigned long long*)onbrT, death, scali);
  hipLaunchKernelGGL(loss_kernel, dim3(1), dim3(256), 0, stream, kde, death, (float*)d_out);
}

// Round 7
// 3569.266 us; speedup vs baseline: 1.6792x; 1.3073x over previous
//
#include <hip/hip_runtime.h>
#include <hip/hip_bf16.h>

#define NPTS 8192
#define DIM 32
#define KKDE 32
#define KRIPS 16
#define DESTNUM 10

__device__ __forceinline__ unsigned long long shfl_xor_u64(unsigned long long v, int m) {
  int lo = __shfl_xor((int)(unsigned)(v & 0xFFFFFFFFull), m, 64);
  int hi = __shfl_xor((int)(unsigned)(v >> 32), m, 64);
  return (((unsigned long long)(unsigned)hi) << 32) | (unsigned)lo;
}

// ---------------- dtype detector: is x bf16-packed or f32? ----------------
__global__ __launch_bounds__(64) void detect_kernel(const unsigned short* __restrict__ x,
                                                    int* __restrict__ flag) {
  int lane = threadIdx.x;
  unsigned u = x[2 * lane];
  int e = (u >> 7) & 0xFF;
  bool pass = (e >= 110 && e <= 130);
  unsigned long long b = __ballot(pass);
  if (lane == 0) flag[0] = (__popcll(b) >= 32) ? 1 : 0;
}

// ---------------- kNN: kde (32-NN) + rips indices (16-NN) ----------------
__global__ __launch_bounds__(256) void knn_kernel(const unsigned short* __restrict__ xh,
                                                  const int* __restrict__ flag,
                                                  float* __restrict__ kde,
                                                  int* __restrict__ rips) {
  __shared__ float row[NPTS];                 // 32 KB
  __shared__ unsigned long long wred[4];
  __shared__ float knnv[KKDE];
  __shared__ int knni[KKDE];
  __shared__ float xis[DIM];
  __shared__ int flagS;
  const int i = blockIdx.x;
  const int t = threadIdx.x;
  if (t == 0) flagS = flag[0];
  __syncthreads();
  const bool isbf16 = (flagS != 0);
  const float* xf = (const float*)xh;
  if (t < DIM)
    xis[t] = isbf16 ? __uint_as_float(((unsigned)xh[i * DIM + t]) << 16)
                    : xf[i * DIM + t];
  __syncthreads();
  float xi[DIM];
#pragma unroll
  for (int q = 0; q < DIM; ++q) xi[q] = xis[q];
  float sqi = 0.f;
#pragma unroll
  for (int q = 0; q < DIM; ++q) sqi = fmaf(xi[q], xi[q], sqi);
  for (int j = t; j < NPTS; j += 256) {
    float xr[DIM];
    if (isbf16) {
      const uint4* xj = (const uint4*)(xh + j * DIM);
#pragma unroll
      for (int q = 0; q < DIM / 8; ++q) {
        uint4 w = xj[q];
        xr[q * 8 + 0] = __uint_as_float(w.x << 16);
        xr[q * 8 + 1] = __uint_as_float(w.x & 0xFFFF0000u);
        xr[q * 8 + 2] = __uint_as_float(w.y << 16);
        xr[q * 8 + 3] = __uint_as_float(w.y & 0xFFFF0000u);
        xr[q * 8 + 4] = __uint_as_float(w.z << 16);
        xr[q * 8 + 5] = __uint_as_float(w.z & 0xFFFF0000u);
        xr[q * 8 + 6] = __uint_as_float(w.w << 16);
        xr[q * 8 + 7] = __uint_as_float(w.w & 0xFFFF0000u);
      }
    } else {
      const float4* xj = (const float4*)(xf + j * DIM);
#pragma unroll
      for (int q = 0; q < DIM / 4; ++q) {
        float4 w = xj[q];
        xr[q * 4 + 0] = w.x;
        xr[q * 4 + 1] = w.y;
        xr[q * 4 + 2] = w.z;
        xr[q * 4 + 3] = w.w;
      }
    }
    float dot = 0.f, sqj = 0.f;
#pragma unroll
    for (int q = 0; q < DIM; ++q) {
      dot = fmaf(xi[q], xr[q], dot);
      sqj = fmaf(xr[q], xr[q], sqj);
    }
    // j==i: dot==sqi==sqj bitwise (identical chains) -> fmaf(-2,s,2s) == 0 exactly
    row[j] = fmaxf(fmaf(-2.f, dot, sqi + sqj), 0.f);
  }
  __syncthreads();
  for (int k = 0; k < KKDE; ++k) {
    unsigned long long best = ~0ull;  // key = (f32 bits << 32) | idx
    for (int j = t; j < NPTS; j += 256) {
      unsigned long long kk = (((unsigned long long)__float_as_uint(row[j])) << 32) | (unsigned)j;
      if (kk < best) best = kk;
    }
#pragma unroll
    for (int m = 32; m; m >>= 1) {
      unsigned long long o = shfl_xor_u64(best, m);
      if (o < best) best = o;
    }
    if ((t & 63) == 0) wred[t >> 6] = best;
    __syncthreads();
    if (t == 0) {
      best = wred[0];
      if (wred[1] < best) best = wred[1];
      if (wred[2] < best) best = wred[2];
      if (wred[3] < best) best = wred[3];
      int bi = (int)(best & 0xFFFFFFFFull);
      knnv[k] = __uint_as_float((unsigned)(best >> 32));
      knni[k] = bi;
      row[bi] = __uint_as_float(0x7F800000u);
    }
    __syncthreads();
  }
  if (t == 0) {
    float s = 0.f;
    for (int k = 0; k < KKDE; ++k) s += expf(knnv[k] * -0.015625f);  // exp(-d2/64)
    kde[i] = s;
  }
  if (t < KRIPS) rips[i * KRIPS + t] = knni[t];
}

// ---------------- max(kde) ----------------
__global__ __launch_bounds__(256) void max_kernel(const float* __restrict__ kde,
                                                  float* __restrict__ scalf) {
  __shared__ float red[256];
  int t = threadIdx.x;
  float m = 0.f;
  for (int p = t; p < NPTS; p += 256) m = fmaxf(m, kde[p]);
  red[t] = m;
  __syncthreads();
  for (int s = 128; s; s >>= 1) {
    if (t < s) red[t] = fmaxf(red[t], red[t + s]);
    __syncthreads();
  }
  if (t == 0) scalf[0] = red[0];
}

// ---------------- normalize + init death ----------------
__global__ __launch_bounds__(256) void norm_kernel(float* __restrict__ kde,
                                                   const float* __restrict__ scalf,
                                                   int* __restrict__ death) {
  int p = blockIdx.x * 256 + threadIdx.x;
  if (p < NPTS) {
    kde[p] = kde[p] / scalf[0];
    death[p] = -1;
  }
}

// ---------------- argmin(kde) ----------------
__global__ __launch_bounds__(256) void argmin_kernel(const float* __restrict__ kde,
                                                     int* __restrict__ scali) {
  __shared__ unsigned long long red[256];
  int t = threadIdx.x;
  unsigned long long best = ~0ull;
  for (int p = t; p < NPTS; p += 256) {
    unsigned long long kk = (((unsigned long long)__float_as_uint(kde[p])) << 32) | (unsigned)p;
    if (kk < best) best = kk;
  }
  red[t] = best;
  __syncthreads();
  for (int s = 128; s; s >>= 1) {
    if (t < s && red[t + s] < red[t]) red[t] = red[t + s];
    __syncthreads();
  }
  if (t == 0) scali[0] = (int)(red[0] & 0xFFFFFFFFull);
}

// ---------------- bitonic sort: order = argsort(-kde) (stable), rank = inverse ----------------
__global__ __launch_bounds__(256) void sort_kernel(const float* __restrict__ kde,
                                                   int* __restrict__ order,
                                                   int* __restrict__ rankp) {
  __shared__ float kv[NPTS];            // 32 KB
  __shared__ unsigned short ki[NPTS];   // 16 KB
  int t = threadIdx.x;
  for (int p = t; p < NPTS; p += 256) { kv[p] = kde[p]; ki[p] = (unsigned short)p; }
  __syncthreads();
  for (int size = 2; size <= NPTS; size <<= 1) {
    for (int stride = size >> 1; stride > 0; stride >>= 1) {
      for (int q = t; q < NPTS / 2; q += 256) {
        int lo = ((q & ~(stride - 1)) << 1) | (q & (stride - 1));
        int hi = lo + stride;
        float va = kv[lo], vb = kv[hi];
        int ia = ki[lo], ib = ki[hi];
        bool aFirst = (va > vb) || (va == vb && ia < ib);
        bool up = ((lo & size) == 0);
        if (up != aFirst) {
          kv[lo] = vb; kv[hi] = va;
          ki[lo] = (unsigned short)ib; ki[hi] = (unsigned short)ia;
        }
      }
      __syncthreads();
    }
  }
  for (int p = t; p < NPTS; p += 256) {
    int idx = ki[p];
    order[p] = idx;
    rankp[idx] = p;
  }
}

// ---------------- ordered neighbor stream (flat: [t*16 + kk]) ----------------
// lane l of the scan's group grp reads u16 (grp*64 + l) = step grp*4+(l>>4), nbr l&15.
__global__ __launch_bounds__(256) void onbr_kernel(const int* __restrict__ order,
                                                   const int* __restrict__ rankp,
                                                   const int* __restrict__ rips,
                                                   unsigned short* __restrict__ onbr) {
  int e = blockIdx.x * 256 + threadIdx.x;  // e < NPTS*KRIPS
  if (e >= NPTS * KRIPS) return;
  int t = e >> 4, kk = e & 15;
  int i = order[t];
  int nbr = rips[i * KRIPS + kk];
  bool valid = rankp[nbr] < t;  // self has rank == t -> invalid, matching ref
  onbr[e] = (unsigned short)(nbr | (valid ? 0x8000 : 0));
}

// ---------------- persistence scan: speculate-then-commit, 4 steps/group ----------------
// Single wave, 48 KB LDS. Lanes 16s..16s+15 own sub-step s of each group.
// Phase 1: all 4 sub-steps find roots in parallel vs group-start state (deep walk
// paid once per 4 steps; compression writes store ancestors -> race-safe).
// Phase 2: sequential commits; revalidation walk from speculated root is usually
// 0-1 hops (at most 3 prior merges). Elder-rule slow path sliced by 16-lane mask,
// identical semantics to the absmax-0.0 round-5 code.
__global__ __launch_bounds__(64) void scan_kernel(const float* __restrict__ kde,
                                                  const int* __restrict__ order,
                                                  const unsigned short* __restrict__ onbr,
                                                  int* __restrict__ death,
                                                  const int* __restrict__ scali) {
  __shared__ float kdeS[NPTS];          // 32 KB
  __shared__ unsigned short par[NPTS];  // 16 KB
  const int lane = threadIdx.x;
  for (int p = lane; p < NPTS; p += 64) { kdeS[p] = kde[p]; par[p] = (unsigned short)p; }
  __syncthreads();
  const int sg = lane >> 4;             // sub-step this lane serves
  unsigned short curD = onbr[lane];     // group 0 descriptors
  int curI = order[sg];                 // i for sub-step sg of group 0
  const int NG = NPTS / 4;
  for (int grp = 0; grp < NG; ++grp) {
    unsigned short nxtD = 0;
    int nxtI = 0;
    if (grp + 1 < NG) {
      nxtD = onbr[(grp + 1) * 64 + lane];
      nxtI = order[(grp + 1) * 4 + sg];
    }
    const int di = curD;
    const int nbr = di & 0x1FFF;
    const bool valid = (di & 0x8000) != 0;
    // ---- phase 1: speculative parallel find (pointer-halving compression) ----
    int r = nbr;
    int prev = -1;
    while (true) {
      int pp = par[r];
      if (__all(pp == r)) break;
      if (prev >= 0) par[prev] = (unsigned short)pp;  // ancestor write: race-safe
      prev = r;
      r = pp;
    }
    if (valid && nbr != r) par[nbr] = (unsigned short)r;  // full compression
    // ---- phase 2: sequential commits ----
#pragma unroll
    for (int s = 0; s < 4; ++s) {
      const unsigned long long smask = 0xFFFFull << (16 * s);
      // revalidate slice s: walk to current root (usually already there);
      // other slices advance opportunistically (reads only).
      while (true) {
        int pp = par[r];
        unsigned long long done = __ballot(pp == r);
        r = pp;
        if ((done & smask) == smask) break;
      }
      unsigned long long vb = __ballot(valid) & smask;
      if (vb != 0) {
        int cl = __ffsll(vb) - 1;
        int gc = __builtin_amdgcn_readlane(r, cl);
        unsigned long long uni = __ballot(!valid || r == gc) & smask;
        if (uni == smask) {
          // all valid roots identical -> g = gc, no deaths
          if (lane == 16 * s) par[curI] = (unsigned short)gc;
        } else {
          // elder-rule argmax (first-occurrence tie-break == jnp.argmax)
          float kr = valid ? kdeS[r] : -1.0f;
          float mx = kr;
#pragma unroll
          for (int mk = 1; mk <= 8; mk <<= 1) mx = fmaxf(mx, __shfl_xor(mx, mk, 64));
          unsigned long long b = __ballot(valid && kr == mx) & smask;
          int kwin = __ffsll(b) - 1;
          int g = __builtin_amdgcn_readlane(r, kwin);
          bool dying = (sg == s) && valid && (r != g);
          if (dying) {
            par[r] = (unsigned short)g;
            death[r] = curI;
          }
          if (lane == 16 * s) par[curI] = (unsigned short)g;
        }
      }  // else: no valid neighbors; par[i] == i already
    }
    curD = nxtD;
    curI = nxtI;
  }
  if (lane == 0) death[order[0]] = scali[0];  // essential pair
}

// ---------------- loss: top-10 persistence, l_change + l_salient (f32 out) ----------------
__global__ __launch_bounds__(256) void loss_kernel(const float* __restrict__ kde,
                                                   const int* __restrict__ death,
                                                   float* __restrict__ out) {
  __shared__ float redv[256];
  __shared__ int redi[256];
  const int t = threadIdx.x;
  int chosen[DESTNUM];
  for (int k = 0; k < DESTNUM; ++k) {
    float bv = -__builtin_inff();
    int bi = 1 << 30;
    for (int p = t; p < NPTS; p += 256) {
      int d = death[p];
      if (d < 0) continue;
      bool used = false;
      for (int c = 0; c < k; ++c) used |= (chosen[c] == p);
      if (used) continue;
      float pers = kde[p] - kde[d];
      if (pers > bv || (pers == bv && p < bi)) { bv = pers; bi = p; }
    }
    redv[t] = bv; redi[t] = bi;
    __syncthreads();
    for (int s = 128; s; s >>= 1) {
      if (t < s) {
        if (redv[t + s] > redv[t] || (redv[t + s] == redv[t] && redi[t + s] < redi[t])) {
          redv[t] = redv[t + s];
          redi[t] = redi[t + s];
        }
      }
      __syncthreads();
    }
    chosen[k] = redi[0];
    __syncthreads();
  }
  float acc = 0.f;
  for (int p = t; p < NPTS; p += 256) {
    int d = death[p];
    if (d < 0) continue;
    bool sal = false;
    for (int c = 0; c < DESTNUM; ++c) sal |= (chosen[c] == p);
    float dv = kde[d];
    float kp = kde[p];
    acc += sal ? ((kp - 1.f) * (kp - 1.f) + dv * dv) : (kp - dv) * (kp - dv);
  }
  redv[t] = acc;
  __syncthreads();
  for (int s = 128; s; s >>= 1) {
    if (t < s) redv[t] += redv[t + s];
    __syncthreads();
  }
  if (t == 0) out[0] = redv[0];
}

extern "C" void kernel_launch(void* const* d_in, const int* in_sizes, int n_in,
                              void* d_out, int out_size, void* d_ws, size_t ws_size,
                              hipStream_t stream) {
  const unsigned short* x = (const unsigned short*)d_in[0];

  float* kde = (float*)d_ws;                      // NPTS f32
  float* scalf = kde + NPTS;                      // [0] = kdemax
  int* scali = (int*)(scalf + 64);                // [0] = argmin idx
  int* flag = scali + 64;                         // [0] = dtype flag (1=bf16, 0=f32)
  int* order = flag + 64;                         // NPTS
  int* rankp = order + NPTS;                      // NPTS
  int* rips = rankp + NPTS;                       // NPTS*KRIPS
  unsigned short* onbr = (unsigned short*)(rips + NPTS * KRIPS);  // NPTS*KRIPS u16
  int* death = (int*)(onbr + NPTS * KRIPS);       // NPTS

  hipLaunchKernelGGL(detect_kernel, dim3(1), dim3(64), 0, stream, x, flag);
  hipLaunchKernelGGL(knn_kernel, dim3(NPTS), dim3(256), 0, stream, x, flag, kde, rips);
  hipLaunchKernelGGL(max_kernel, dim3(1), dim3(256), 0, stream, kde, scalf);
  hipLaunchKernelGGL(norm_kernel, dim3(NPTS / 256), dim3(256), 0, stream, kde, scalf, death);
  hipLaunchKernelGGL(argmin_kernel, dim3(1), dim3(256), 0, stream, kde, scali);
  hipLaunchKernelGGL(sort_kernel, dim3(1), dim3(256), 0, stream, kde, order, rankp);
  hipLaunchKernelGGL(onbr_kernel, dim3(NPTS * KRIPS / 256), dim3(256), 0, stream,
                     order, rankp, rips, onbr);
  hipLaunchKernelGGL(scan_kernel, dim3(1), dim3(64), 0, stream, kde, order, onbr, death, scali);
  hipLaunchKernelGGL(loss_kernel, dim3(1), dim3(256), 0, stream, kde, death, (float*)d_out);
}

// Round 8
// 2966.730 us; speedup vs baseline: 2.0203x; 1.2031x over previous
//
#include <hip/hip_runtime.h>
#include <hip/hip_bf16.h>

#define NPTS 8192
#define DIM 32
#define KKDE 32
#define KRIPS 16
#define DESTNUM 10

__device__ __forceinline__ unsigned long long shfl_xor_u64(unsigned long long v, int m) {
  int lo = __shfl_xor((int)(unsigned)(v & 0xFFFFFFFFull), m, 64);
  int hi = __shfl_xor((int)(unsigned)(v >> 32), m, 64);
  return (((unsigned long long)(unsigned)hi) << 32) | (unsigned)lo;
}

// ---------------- dtype detector: is x bf16-packed or f32? ----------------
__global__ __launch_bounds__(64) void detect_kernel(const unsigned short* __restrict__ x,
                                                    int* __restrict__ flag) {
  int lane = threadIdx.x;
  unsigned u = x[2 * lane];
  int e = (u >> 7) & 0xFF;
  bool pass = (e >= 110 && e <= 130);
  unsigned long long b = __ballot(pass);
  if (lane == 0) flag[0] = (__popcll(b) >= 32) ? 1 : 0;
}

// ---------------- kNN: kde (32-NN) + rips indices (16-NN) ----------------
__global__ __launch_bounds__(256) void knn_kernel(const unsigned short* __restrict__ xh,
                                                  const int* __restrict__ flag,
                                                  float* __restrict__ kde,
                                                  int* __restrict__ rips) {
  __shared__ float row[NPTS];                 // 32 KB
  __shared__ unsigned long long wred[4];
  __shared__ float knnv[KKDE];
  __shared__ int knni[KKDE];
  __shared__ float xis[DIM];
  __shared__ int flagS;
  const int i = blockIdx.x;
  const int t = threadIdx.x;
  if (t == 0) flagS = flag[0];
  __syncthreads();
  const bool isbf16 = (flagS != 0);
  const float* xf = (const float*)xh;
  if (t < DIM)
    xis[t] = isbf16 ? __uint_as_float(((unsigned)xh[i * DIM + t]) << 16)
                    : xf[i * DIM + t];
  __syncthreads();
  float xi[DIM];
#pragma unroll
  for (int q = 0; q < DIM; ++q) xi[q] = xis[q];
  float sqi = 0.f;
#pragma unroll
  for (int q = 0; q < DIM; ++q) sqi = fmaf(xi[q], xi[q], sqi);
  for (int j = t; j < NPTS; j += 256) {
    float xr[DIM];
    if (isbf16) {
      const uint4* xj = (const uint4*)(xh + j * DIM);
#pragma unroll
      for (int q = 0; q < DIM / 8; ++q) {
        uint4 w = xj[q];
        xr[q * 8 + 0] = __uint_as_float(w.x << 16);
        xr[q * 8 + 1] = __uint_as_float(w.x & 0xFFFF0000u);
        xr[q * 8 + 2] = __uint_as_float(w.y << 16);
        xr[q * 8 + 3] = __uint_as_float(w.y & 0xFFFF0000u);
        xr[q * 8 + 4] = __uint_as_float(w.z << 16);
        xr[q * 8 + 5] = __uint_as_float(w.z & 0xFFFF0000u);
        xr[q * 8 + 6] = __uint_as_float(w.w << 16);
        xr[q * 8 + 7] = __uint_as_float(w.w & 0xFFFF0000u);
      }
    } else {
      const float4* xj = (const float4*)(xf + j * DIM);
#pragma unroll
      for (int q = 0; q < DIM / 4; ++q) {
        float4 w = xj[q];
        xr[q * 4 + 0] = w.x;
        xr[q * 4 + 1] = w.y;
        xr[q * 4 + 2] = w.z;
        xr[q * 4 + 3] = w.w;
      }
    }
    float dot = 0.f, sqj = 0.f;
#pragma unroll
    for (int q = 0; q < DIM; ++q) {
      dot = fmaf(xi[q], xr[q], dot);
      sqj = fmaf(xr[q], xr[q], sqj);
    }
    // j==i: dot==sqi==sqj bitwise (identical chains) -> fmaf(-2,s,2s) == 0 exactly
    row[j] = fmaxf(fmaf(-2.f, dot, sqi + sqj), 0.f);
  }
  __syncthreads();
  for (int k = 0; k < KKDE; ++k) {
    unsigned long long best = ~0ull;  // key = (f32 bits << 32) | idx
    for (int j = t; j < NPTS; j += 256) {
      unsigned long long kk = (((unsigned long long)__float_as_uint(row[j])) << 32) | (unsigned)j;
      if (kk < best) best = kk;
    }
#pragma unroll
    for (int m = 32; m; m >>= 1) {
      unsigned long long o = shfl_xor_u64(best, m);
      if (o < best) best = o;
    }
    if ((t & 63) == 0) wred[t >> 6] = best;
    __syncthreads();
    if (t == 0) {
      best = wred[0];
      if (wred[1] < best) best = wred[1];
      if (wred[2] < best) best = wred[2];
      if (wred[3] < best) best = wred[3];
      int bi = (int)(best & 0xFFFFFFFFull);
      knnv[k] = __uint_as_float((unsigned)(best >> 32));
      knni[k] = bi;
      row[bi] = __uint_as_float(0x7F800000u);
    }
    __syncthreads();
  }
  if (t == 0) {
    float s = 0.f;
    for (int k = 0; k < KKDE; ++k) s += expf(knnv[k] * -0.015625f);  // exp(-d2/64)
    kde[i] = s;
  }
  if (t < KRIPS) rips[i * KRIPS + t] = knni[t];
}

// ---------------- max(kde) ----------------
__global__ __launch_bounds__(256) void max_kernel(const float* __restrict__ kde,
                                                  float* __restrict__ scalf) {
  __shared__ float red[256];
  int t = threadIdx.x;
  float m = 0.f;
  for (int p = t; p < NPTS; p += 256) m = fmaxf(m, kde[p]);
  red[t] = m;
  __syncthreads();
  for (int s = 128; s; s >>= 1) {
    if (t < s) red[t] = fmaxf(red[t], red[t + s]);
    __syncthreads();
  }
  if (t == 0) scalf[0] = red[0];
}

// ---------------- normalize + init death ----------------
__global__ __launch_bounds__(256) void norm_kernel(float* __restrict__ kde,
                                                   const float* __restrict__ scalf,
                                                   int* __restrict__ death) {
  int p = blockIdx.x * 256 + threadIdx.x;
  if (p < NPTS) {
    kde[p] = kde[p] / scalf[0];
    death[p] = -1;
  }
}

// ---------------- argmin(kde) ----------------
__global__ __launch_bounds__(256) void argmin_kernel(const float* __restrict__ kde,
                                                     int* __restrict__ scali) {
  __shared__ unsigned long long red[256];
  int t = threadIdx.x;
  unsigned long long best = ~0ull;
  for (int p = t; p < NPTS; p += 256) {
    unsigned long long kk = (((unsigned long long)__float_as_uint(kde[p])) << 32) | (unsigned)p;
    if (kk < best) best = kk;
  }
  red[t] = best;
  __syncthreads();
  for (int s = 128; s; s >>= 1) {
    if (t < s && red[t + s] < red[t]) red[t] = red[t + s];
    __syncthreads();
  }
  if (t == 0) scali[0] = (int)(red[0] & 0xFFFFFFFFull);
}

// ---------------- bitonic sort: order = argsort(-kde) (stable), rank = inverse ----------------
__global__ __launch_bounds__(256) void sort_kernel(const float* __restrict__ kde,
                                                   int* __restrict__ order,
                                                   int* __restrict__ rankp) {
  __shared__ float kv[NPTS];            // 32 KB
  __shared__ unsigned short ki[NPTS];   // 16 KB
  int t = threadIdx.x;
  for (int p = t; p < NPTS; p += 256) { kv[p] = kde[p]; ki[p] = (unsigned short)p; }
  __syncthreads();
  for (int size = 2; size <= NPTS; size <<= 1) {
    for (int stride = size >> 1; stride > 0; stride >>= 1) {
      for (int q = t; q < NPTS / 2; q += 256) {
        int lo = ((q & ~(stride - 1)) << 1) | (q & (stride - 1));
        int hi = lo + stride;
        float va = kv[lo], vb = kv[hi];
        int ia = ki[lo], ib = ki[hi];
        bool aFirst = (va > vb) || (va == vb && ia < ib);
        bool up = ((lo & size) == 0);
        if (up != aFirst) {
          kv[lo] = vb; kv[hi] = va;
          ki[lo] = (unsigned short)ib; ki[hi] = (unsigned short)ia;
        }
      }
      __syncthreads();
    }
  }
  for (int p = t; p < NPTS; p += 256) {
    int idx = ki[p];
    order[p] = idx;
    rankp[idx] = p;
  }
}

// ---------------- ordered neighbor stream (flat: [t*16 + kk]) ----------------
__global__ __launch_bounds__(256) void onbr_kernel(const int* __restrict__ order,
                                                   const int* __restrict__ rankp,
                                                   const int* __restrict__ rips,
                                                   unsigned short* __restrict__ onbr) {
  int e = blockIdx.x * 256 + threadIdx.x;  // e < NPTS*KRIPS
  if (e >= NPTS * KRIPS) return;
  int t = e >> 4, kk = e & 15;
  int i = order[t];
  int nbr = rips[i * KRIPS + kk];
  bool valid = rankp[nbr] < t;  // self has rank == t -> invalid, matching ref
  onbr[e] = (unsigned short)(nbr | (valid ? 0x8000 : 0));
}

// ---------------- persistence scan: speculate + group fast path ----------------
// Single wave, 48 KB LDS. Lanes 16s..16s+15 own sub-step s of each group of 4.
// Phase 1: parallel find with pointer-halving compression (race-safe: all writes
// store ancestors). Fast path: if every slice's valid roots are uniform AND no
// root collides with one of the group's 4 inserted points, the commits are 4
// independent singleton-attaches done in parallel (no deaths possible).
// Slow path: R7's sequential revalidate+elder-argmax commits, proven absmax 0.0.
__global__ __launch_bounds__(64) void scan_kernel(const float* __restrict__ kde,
                                                  const int* __restrict__ order,
                                                  const unsigned short* __restrict__ onbr,
                                                  int* __restrict__ death,
                                                  const int* __restrict__ scali) {
  __shared__ float kdeS[NPTS];          // 32 KB
  __shared__ unsigned short par[NPTS];  // 16 KB
  const int lane = threadIdx.x;
  for (int p = lane; p < NPTS; p += 64) { kdeS[p] = kde[p]; par[p] = (unsigned short)p; }
  __syncthreads();
  const int sg = lane >> 4;             // sub-step this lane serves
  const int4* ord4 = (const int4*)order;
  unsigned short curD = onbr[lane];     // group 0 descriptors
  int4 curI = ord4[0];                  // uniform (scalar) load of the 4 inserted points
  const int NG = NPTS / 4;
  for (int grp = 0; grp < NG; ++grp) {
    unsigned short nxtD = 0;
    int4 nxtI = make_int4(0, 0, 0, 0);
    if (grp + 1 < NG) {
      nxtD = onbr[(grp + 1) * 64 + lane];
      nxtI = ord4[grp + 1];
    }
    const int di = curD;
    const int nbr = di & 0x1FFF;
    const bool valid = (di & 0x8000) != 0;
    const int iMine = (sg == 0) ? curI.x : (sg == 1) ? curI.y : (sg == 2) ? curI.z : curI.w;
    // ---- phase 1: speculative parallel find (pointer-halving compression) ----
    int r = nbr;
    int prev = -1;
    while (true) {
      int pp = par[r];
      if (__all(pp == r)) break;
      if (prev >= 0) par[prev] = (unsigned short)pp;  // ancestor write: race-safe
      prev = r;
      r = pp;
    }
    if (valid && nbr != r) par[nbr] = (unsigned short)r;
    const unsigned long long vbAll = __ballot(valid);
    // per-slice candidate root gc_s = root of first valid lane (uniform SGPR math)
    const unsigned long long vb0 = vbAll & 0xFFFFull;
    const unsigned long long vb1 = (vbAll >> 16) & 0xFFFFull;
    const unsigned long long vb2 = (vbAll >> 32) & 0xFFFFull;
    const unsigned long long vb3 = (vbAll >> 48) & 0xFFFFull;
    const int gc0 = vb0 ? __builtin_amdgcn_readlane(r, __ffsll(vb0) - 1) : curI.x;
    const int gc1 = vb1 ? __builtin_amdgcn_readlane(r, 16 + __ffsll(vb1) - 1) : curI.y;
    const int gc2 = vb2 ? __builtin_amdgcn_readlane(r, 32 + __ffsll(vb2) - 1) : curI.z;
    const int gc3 = vb3 ? __builtin_amdgcn_readlane(r, 48 + __ffsll(vb3) - 1) : curI.w;
    const int gcMine = (sg == 0) ? gc0 : (sg == 1) ? gc1 : (sg == 2) ? gc2 : gc3;
    const bool uniOk = !valid || (r == gcMine);
    const bool collide =
        valid && (r == curI.x || r == curI.y || r == curI.z || r == curI.w);
    if (__all(uniOk && !collide)) {
      // ---- fast path: 4 independent singleton-attaches, no deaths ----
      if ((lane & 15) == 0) par[iMine] = (unsigned short)gcMine;
    } else {
      // ---- slow path: sequential commits (R7 verbatim semantics) ----
#pragma unroll
      for (int s = 0; s < 4; ++s) {
        const unsigned long long smask = 0xFFFFull << (16 * s);
        // revalidate slice s to the current root; others advance opportunistically
        while (true) {
          int pp = par[r];
          unsigned long long done = __ballot(pp == r);
          r = pp;
          if ((done & smask) == smask) break;
        }
        unsigned long long vb = vbAll & smask;
        if (vb != 0) {
          int cl = __ffsll(vb) - 1;
          int gc = __builtin_amdgcn_readlane(r, cl);
          unsigned long long uni = __ballot(!valid || r == gc) & smask;
          if (uni == smask) {
            if (lane == 16 * s) par[iMine] = (unsigned short)gc;
          } else {
            // elder-rule argmax (first-occurrence tie-break == jnp.argmax)
            float kr = valid ? kdeS[r] : -1.0f;
            float mx = kr;
#pragma unroll
            for (int mk = 1; mk <= 8; mk <<= 1) mx = fmaxf(mx, __shfl_xor(mx, mk, 64));
            unsigned long long b = __ballot(valid && kr == mx) & smask;
            int kwin = __ffsll(b) - 1;
            int g = __builtin_amdgcn_readlane(r, kwin);
            bool dying = (sg == s) && valid && (r != g);
            if (dying) {
              par[r] = (unsigned short)g;
              death[r] = iMine;
            }
            if (lane == 16 * s) par[iMine] = (unsigned short)g;
          }
        }  // else: no valid neighbors; par[i] == i already
      }
    }
    curD = nxtD;
    curI = nxtI;
  }
  if (lane == 0) death[order[0]] = scali[0];  // essential pair
}

// ---------------- loss: top-10 persistence, l_change + l_salient (f32 out) ----------------
__global__ __launch_bounds__(256) void loss_kernel(const float* __restrict__ kde,
                                                   const int* __restrict__ death,
                                                   float* __restrict__ out) {
  __shared__ float redv[256];
  __shared__ int redi[256];
  const int t = threadIdx.x;
  int chosen[DESTNUM];
  for (int k = 0; k < DESTNUM; ++k) {
    float bv = -__builtin_inff();
    int bi = 1 << 30;
    for (int p = t; p < NPTS; p += 256) {
      int d = death[p];
      if (d < 0) continue;
      bool used = false;
      for (int c = 0; c < k; ++c) used |= (chosen[c] == p);
      if (used) continue;
      float pers = kde[p] - kde[d];
      if (pers > bv || (pers == bv && p < bi)) { bv = pers; bi = p; }
    }
    redv[t] = bv; redi[t] = bi;
    __syncthreads();
    for (int s = 128; s; s >>= 1) {
      if (t < s) {
        if (redv[t + s] > redv[t] || (redv[t + s] == redv[t] && redi[t + s] < redi[t])) {
          redv[t] = redv[t + s];
          redi[t] = redi[t + s];
        }
      }
      __syncthreads();
    }
    chosen[k] = redi[0];
    __syncthreads();
  }
  float acc = 0.f;
  for (int p = t; p < NPTS; p += 256) {
    int d = death[p];
    if (d < 0) continue;
    bool sal = false;
    for (int c = 0; c < DESTNUM; ++c) sal |= (chosen[c] == p);
    float dv = kde[d];
    float kp = kde[p];
    acc += sal ? ((kp - 1.f) * (kp - 1.f) + dv * dv) : (kp - dv) * (kp - dv);
  }
  redv[t] = acc;
  __syncthreads();
  for (int s = 128; s; s >>= 1) {
    if (t < s) redv[t] += redv[t + s];
    __syncthreads();
  }
  if (t == 0) out[0] = redv[0];
}

extern "C" void kernel_launch(void* const* d_in, const int* in_sizes, int n_in,
                              void* d_out, int out_size, void* d_ws, size_t ws_size,
                              hipStream_t stream) {
  const unsigned short* x = (const unsigned short*)d_in[0];

  float* kde = (float*)d_ws;                      // NPTS f32
  float* scalf = kde + NPTS;                      // [0] = kdemax
  int* scali = (int*)(scalf + 64);                // [0] = argmin idx
  int* flag = scali + 64;                         // [0] = dtype flag (1=bf16, 0=f32)
  int* order = flag + 64;                         // NPTS (16B-aligned for int4 loads)
  int* rankp = order + NPTS;                      // NPTS
  int* rips = rankp + NPTS;                       // NPTS*KRIPS
  unsigned short* onbr = (unsigned short*)(rips + NPTS * KRIPS);  // NPTS*KRIPS u16
  int* death = (int*)(onbr + NPTS * KRIPS);       // NPTS

  hipLaunchKernelGGL(detect_kernel, dim3(1), dim3(64), 0, stream, x, flag);
  hipLaunchKernelGGL(knn_kernel, dim3(NPTS), dim3(256), 0, stream, x, flag, kde, rips);
  hipLaunchKernelGGL(max_kernel, dim3(1), dim3(256), 0, stream, kde, scalf);
  hipLaunchKernelGGL(norm_kernel, dim3(NPTS / 256), dim3(256), 0, stream, kde, scalf, death);
  hipLaunchKernelGGL(argmin_kernel, dim3(1), dim3(256), 0, stream, kde, scali);
  hipLaunchKernelGGL(sort_kernel, dim3(1), dim3(256), 0, stream, kde, order, rankp);
  hipLaunchKernelGGL(onbr_kernel, dim3(NPTS * KRIPS / 256), dim3(256), 0, stream,
                     order, rankp, rips, onbr);
  hipLaunchKernelGGL(scan_kernel, dim3(1), dim3(64), 0, stream, kde, order, onbr, death, scali);
  hipLaunchKernelGGL(loss_kernel, dim3(1), dim3(256), 0, stream, kde, death, (float*)d_out);
}

// Round 9
// 2586.583 us; speedup vs baseline: 2.3172x; 1.1470x over previous
//
#include <hip/hip_runtime.h>
#include <hip/hip_bf16.h>

#define NPTS 8192
#define DIM 32
#define KKDE 32
#define KRIPS 16
#define DESTNUM 10

__device__ __forceinline__ unsigned long long shfl_xor_u64(unsigned long long v, int m) {
  int lo = __shfl_xor((int)(unsigned)(v & 0xFFFFFFFFull), m, 64);
  int hi = __shfl_xor((int)(unsigned)(v >> 32), m, 64);
  return (((unsigned long long)(unsigned)hi) << 32) | (unsigned)lo;
}

// ---------------- dtype detector: is x bf16-packed or f32? ----------------
__global__ __launch_bounds__(64) void detect_kernel(const unsigned short* __restrict__ x,
                                                    int* __restrict__ flag) {
  int lane = threadIdx.x;
  unsigned u = x[2 * lane];
  int e = (u >> 7) & 0xFF;
  bool pass = (e >= 110 && e <= 130);
  unsigned long long b = __ballot(pass);
  if (lane == 0) flag[0] = (__popcll(b) >= 32) ? 1 : 0;
}

// ---------------- kNN: kde (32-NN) + rips indices (16-NN) ----------------
__global__ __launch_bounds__(256) void knn_kernel(const unsigned short* __restrict__ xh,
                                                  const int* __restrict__ flag,
                                                  float* __restrict__ kde,
                                                  int* __restrict__ rips) {
  __shared__ float row[NPTS];                 // 32 KB
  __shared__ unsigned long long wred[4];
  __shared__ float knnv[KKDE];
  __shared__ int knni[KKDE];
  __shared__ float xis[DIM];
  __shared__ int flagS;
  const int i = blockIdx.x;
  const int t = threadIdx.x;
  if (t == 0) flagS = flag[0];
  __syncthreads();
  const bool isbf16 = (flagS != 0);
  const float* xf = (const float*)xh;
  if (t < DIM)
    xis[t] = isbf16 ? __uint_as_float(((unsigned)xh[i * DIM + t]) << 16)
                    : xf[i * DIM + t];
  __syncthreads();
  float xi[DIM];
#pragma unroll
  for (int q = 0; q < DIM; ++q) xi[q] = xis[q];
  float sqi = 0.f;
#pragma unroll
  for (int q = 0; q < DIM; ++q) sqi = fmaf(xi[q], xi[q], sqi);
  for (int j = t; j < NPTS; j += 256) {
    float xr[DIM];
    if (isbf16) {
      const uint4* xj = (const uint4*)(xh + j * DIM);
#pragma unroll
      for (int q = 0; q < DIM / 8; ++q) {
        uint4 w = xj[q];
        xr[q * 8 + 0] = __uint_as_float(w.x << 16);
        xr[q * 8 + 1] = __uint_as_float(w.x & 0xFFFF0000u);
        xr[q * 8 + 2] = __uint_as_float(w.y << 16);
        xr[q * 8 + 3] = __uint_as_float(w.y & 0xFFFF0000u);
        xr[q * 8 + 4] = __uint_as_float(w.z << 16);
        xr[q * 8 + 5] = __uint_as_float(w.z & 0xFFFF0000u);
        xr[q * 8 + 6] = __uint_as_float(w.w << 16);
        xr[q * 8 + 7] = __uint_as_float(w.w & 0xFFFF0000u);
      }
    } else {
      const float4* xj = (const float4*)(xf + j * DIM);
#pragma unroll
      for (int q = 0; q < DIM / 4; ++q) {
        float4 w = xj[q];
        xr[q * 4 + 0] = w.x;
        xr[q * 4 + 1] = w.y;
        xr[q * 4 + 2] = w.z;
        xr[q * 4 + 3] = w.w;
      }
    }
    float dot = 0.f, sqj = 0.f;
#pragma unroll
    for (int q = 0; q < DIM; ++q) {
      dot = fmaf(xi[q], xr[q], dot);
      sqj = fmaf(xr[q], xr[q], sqj);
    }
    // j==i: dot==sqi==sqj bitwise (identical chains) -> fmaf(-2,s,2s) == 0 exactly
    row[j] = fmaxf(fmaf(-2.f, dot, sqi + sqj), 0.f);
  }
  __syncthreads();
  for (int k = 0; k < KKDE; ++k) {
    unsigned long long best = ~0ull;  // key = (f32 bits << 32) | idx
    for (int j = t; j < NPTS; j += 256) {
      unsigned long long kk = (((unsigned long long)__float_as_uint(row[j])) << 32) | (unsigned)j;
      if (kk < best) best = kk;
    }
#pragma unroll
    for (int m = 32; m; m >>= 1) {
      unsigned long long o = shfl_xor_u64(best, m);
      if (o < best) best = o;
    }
    if ((t & 63) == 0) wred[t >> 6] = best;
    __syncthreads();
    if (t == 0) {
      best = wred[0];
      if (wred[1] < best) best = wred[1];
      if (wred[2] < best) best = wred[2];
      if (wred[3] < best) best = wred[3];
      int bi = (int)(best & 0xFFFFFFFFull);
      knnv[k] = __uint_as_float((unsigned)(best >> 32));
      knni[k] = bi;
      row[bi] = __uint_as_float(0x7F800000u);
    }
    __syncthreads();
  }
  if (t == 0) {
    float s = 0.f;
    for (int k = 0; k < KKDE; ++k) s += expf(knnv[k] * -0.015625f);  // exp(-d2/64)
    kde[i] = s;
  }
  if (t < KRIPS) rips[i * KRIPS + t] = knni[t];
}

// ---------------- max(kde) ----------------
__global__ __launch_bounds__(256) void max_kernel(const float* __restrict__ kde,
                                                  float* __restrict__ scalf) {
  __shared__ float red[256];
  int t = threadIdx.x;
  float m = 0.f;
  for (int p = t; p < NPTS; p += 256) m = fmaxf(m, kde[p]);
  red[t] = m;
  __syncthreads();
  for (int s = 128; s; s >>= 1) {
    if (t < s) red[t] = fmaxf(red[t], red[t + s]);
    __syncthreads();
  }
  if (t == 0) scalf[0] = red[0];
}

// ---------------- normalize + init death ----------------
__global__ __launch_bounds__(256) void norm_kernel(float* __restrict__ kde,
                                                   const float* __restrict__ scalf,
                                                   int* __restrict__ death) {
  int p = blockIdx.x * 256 + threadIdx.x;
  if (p < NPTS) {
    kde[p] = kde[p] / scalf[0];
    death[p] = -1;
  }
}

// ---------------- argmin(kde) ----------------
__global__ __launch_bounds__(256) void argmin_kernel(const float* __restrict__ kde,
                                                     int* __restrict__ scali) {
  __shared__ unsigned long long red[256];
  int t = threadIdx.x;
  unsigned long long best = ~0ull;
  for (int p = t; p < NPTS; p += 256) {
    unsigned long long kk = (((unsigned long long)__float_as_uint(kde[p])) << 32) | (unsigned)p;
    if (kk < best) best = kk;
  }
  red[t] = best;
  __syncthreads();
  for (int s = 128; s; s >>= 1) {
    if (t < s && red[t + s] < red[t]) red[t] = red[t + s];
    __syncthreads();
  }
  if (t == 0) scali[0] = (int)(red[0] & 0xFFFFFFFFull);
}

// ---------------- bitonic sort: order = argsort(-kde) (stable), rank = inverse ----------------
__global__ __launch_bounds__(256) void sort_kernel(const float* __restrict__ kde,
                                                   int* __restrict__ order,
                                                   int* __restrict__ rankp) {
  __shared__ float kv[NPTS];            // 32 KB
  __shared__ unsigned short ki[NPTS];   // 16 KB
  int t = threadIdx.x;
  for (int p = t; p < NPTS; p += 256) { kv[p] = kde[p]; ki[p] = (unsigned short)p; }
  __syncthreads();
  for (int size = 2; size <= NPTS; size <<= 1) {
    for (int stride = size >> 1; stride > 0; stride >>= 1) {
      for (int q = t; q < NPTS / 2; q += 256) {
        int lo = ((q & ~(stride - 1)) << 1) | (q & (stride - 1));
        int hi = lo + stride;
        float va = kv[lo], vb = kv[hi];
        int ia = ki[lo], ib = ki[hi];
        bool aFirst = (va > vb) || (va == vb && ia < ib);
        bool up = ((lo & size) == 0);
        if (up != aFirst) {
          kv[lo] = vb; kv[hi] = va;
          ki[lo] = (unsigned short)ib; ki[hi] = (unsigned short)ia;
        }
      }
      __syncthreads();
    }
  }
  for (int p = t; p < NPTS; p += 256) {
    int idx = ki[p];
    order[p] = idx;
    rankp[idx] = p;
  }
}

// ---------------- ordered neighbor stream (flat: [t*16 + kk]) ----------------
__global__ __launch_bounds__(256) void onbr_kernel(const int* __restrict__ order,
                                                   const int* __restrict__ rankp,
                                                   const int* __restrict__ rips,
                                                   unsigned short* __restrict__ onbr) {
  int e = blockIdx.x * 256 + threadIdx.x;  // e < NPTS*KRIPS
  if (e >= NPTS * KRIPS) return;
  int t = e >> 4, kk = e & 15;
  int i = order[t];
  int nbr = rips[i * KRIPS + kk];
  bool valid = rankp[nbr] < t;  // self has rank == t -> invalid, matching ref
  onbr[e] = (unsigned short)(nbr | (valid ? 0x8000 : 0));
}

// ---------------- persistence scan: eagerly-compressed union-find ----------------
// Single wave, 48 KB LDS. INVARIANT: root[p] is always the true root (depth<=1),
// so a find is ONE ds_read. After each merge (rare) the invariant is restored by
// one wave-parallel halving pass: stale chains are exactly p->d->g, and every
// gather target is a fixed-point of the pass, so it is race-free without barriers.
// Group-of-4 fast path (uniform roots, no collision with in-group points) commits
// 4 singleton-attaches in parallel; slow path = R7/R8's proven elder-rule commits.
__global__ __launch_bounds__(64) void scan_kernel(const float* __restrict__ kde,
                                                  const int* __restrict__ order,
                                                  const unsigned short* __restrict__ onbr,
                                                  int* __restrict__ death,
                                                  const int* __restrict__ scali) {
  __shared__ float kdeS[NPTS];          // 32 KB
  __shared__ unsigned short root[NPTS]; // 16 KB
  const int lane = threadIdx.x;
  for (int p = lane; p < NPTS; p += 64) { kdeS[p] = kde[p]; root[p] = (unsigned short)p; }
  __syncthreads();
  const int sg = lane >> 4;             // sub-step this lane serves
  const int4* ord4 = (const int4*)order;
  unsigned long long* root64 = (unsigned long long*)root;
  unsigned short curD = onbr[lane];     // group 0 descriptors
  int4 curI = ord4[0];
  const int NG = NPTS / 4;
  for (int grp = 0; grp < NG; ++grp) {
    unsigned short nxtD = 0;
    int4 nxtI = make_int4(0, 0, 0, 0);
    if (grp + 1 < NG) {
      nxtD = onbr[(grp + 1) * 64 + lane];
      nxtI = ord4[grp + 1];
    }
    const int di = curD;
    const int nbr = di & 0x1FFF;
    const bool valid = (di & 0x8000) != 0;
    const int iMine = (sg == 0) ? curI.x : (sg == 1) ? curI.y : (sg == 2) ? curI.z : curI.w;
    const int rd = root[nbr];           // single-hop find (invariant)
    const unsigned long long vbAll = __ballot(valid);
    const unsigned long long vb0 = vbAll & 0xFFFFull;
    const unsigned long long vb1 = (vbAll >> 16) & 0xFFFFull;
    const unsigned long long vb2 = (vbAll >> 32) & 0xFFFFull;
    const unsigned long long vb3 = (vbAll >> 48) & 0xFFFFull;
    const int gc0 = vb0 ? __builtin_amdgcn_readlane(rd, __ffsll(vb0) - 1) : curI.x;
    const int gc1 = vb1 ? __builtin_amdgcn_readlane(rd, 16 + __ffsll(vb1) - 1) : curI.y;
    const int gc2 = vb2 ? __builtin_amdgcn_readlane(rd, 32 + __ffsll(vb2) - 1) : curI.z;
    const int gc3 = vb3 ? __builtin_amdgcn_readlane(rd, 48 + __ffsll(vb3) - 1) : curI.w;
    const int gcMine = (sg == 0) ? gc0 : (sg == 1) ? gc1 : (sg == 2) ? gc2 : gc3;
    const bool uniOk = !valid || (rd == gcMine);
    const bool collide =
        valid && (rd == curI.x || rd == curI.y || rd == curI.z || rd == curI.w);
    if (__all(uniOk && !collide)) {
      // ---- fast path: 4 independent singleton-attaches, no deaths ----
      if ((lane & 15) == 0) root[iMine] = (unsigned short)gcMine;
    } else {
      // ---- slow path: sequential commits under the invariant ----
#pragma unroll
      for (int s = 0; s < 4; ++s) {
        const unsigned long long smask = 0xFFFFull << (16 * s);
        const int rc = (s == 0) ? rd : (int)root[nbr];  // 1-hop re-read (invariant)
        unsigned long long vb = vbAll & smask;
        if (vb != 0) {
          int cl = __ffsll(vb) - 1;
          int gc = __builtin_amdgcn_readlane(rc, cl);
          unsigned long long uni = __ballot(!valid || rc == gc) & smask;
          if (uni == smask) {
            if (lane == 16 * s) root[iMine] = (unsigned short)gc;
          } else {
            // elder-rule argmax (butterfly stays within the 16-lane slice;
            // first-occurrence tie-break == jnp.argmax)
            float kr = valid ? kdeS[rc] : -1.0f;
            float mx = kr;
#pragma unroll
            for (int mk = 1; mk <= 8; mk <<= 1) mx = fmaxf(mx, __shfl_xor(mx, mk, 64));
            unsigned long long b = __ballot(valid && kr == mx) & smask;
            int kwin = __ffsll(b) - 1;
            int g = __builtin_amdgcn_readlane(rc, kwin);
            bool dying = (sg == s) && valid && (rc != g);
            if (dying) {
              root[rc] = (unsigned short)g;   // duplicate same-value writes: benign
              death[rc] = iMine;
            }
            if (lane == 16 * s) root[iMine] = (unsigned short)g;
            // restore full compression: chains are exactly p->d->g; one halving
            // pass (all gather targets are fixed-points -> race-free)
#pragma unroll 1
            for (int it = 0; it < NPTS / 256; ++it) {
              int idx = it * 64 + lane;
              unsigned long long w = root64[idx];
              unsigned e0 = (unsigned)(w & 0xFFFFull);
              unsigned e1 = (unsigned)((w >> 16) & 0xFFFFull);
              unsigned e2 = (unsigned)((w >> 32) & 0xFFFFull);
              unsigned e3 = (unsigned)((w >> 48) & 0xFFFFull);
              e0 = root[e0]; e1 = root[e1]; e2 = root[e2]; e3 = root[e3];
              root64[idx] = (unsigned long long)e0 | ((unsigned long long)e1 << 16) |
                            ((unsigned long long)e2 << 32) | ((unsigned long long)e3 << 48);
            }
          }
        }  // else: no valid neighbors; root[i] == i already
      }
    }
    curD = nxtD;
    curI = nxtI;
  }
  if (lane == 0) death[order[0]] = scali[0];  // essential pair
}

// ---------------- loss: top-10 persistence, l_change + l_salient (f32 out) ----------------
__global__ __launch_bounds__(256) void loss_kernel(const float* __restrict__ kde,
                                                   const int* __restrict__ death,
                                                   float* __restrict__ out) {
  __shared__ float redv[256];
  __shared__ int redi[256];
  const int t = threadIdx.x;
  int chosen[DESTNUM];
  for (int k = 0; k < DESTNUM; ++k) {
    float bv = -__builtin_inff();
    int bi = 1 << 30;
    for (int p = t; p < NPTS; p += 256) {
      int d = death[p];
      if (d < 0) continue;
      bool used = false;
      for (int c = 0; c < k; ++c) used |= (chosen[c] == p);
      if (used) continue;
      float pers = kde[p] - kde[d];
      if (pers > bv || (pers == bv && p < bi)) { bv = pers; bi = p; }
    }
    redv[t] = bv; redi[t] = bi;
    __syncthreads();
    for (int s = 128; s; s >>= 1) {
      if (t < s) {
        if (redv[t + s] > redv[t] || (redv[t + s] == redv[t] && redi[t + s] < redi[t])) {
          redv[t] = redv[t + s];
          redi[t] = redi[t + s];
        }
      }
      __syncthreads();
    }
    chosen[k] = redi[0];
    __syncthreads();
  }
  float acc = 0.f;
  for (int p = t; p < NPTS; p += 256) {
    int d = death[p];
    if (d < 0) continue;
    bool sal = false;
    for (int c = 0; c < DESTNUM; ++c) sal |= (chosen[c] == p);
    float dv = kde[d];
    float kp = kde[p];
    acc += sal ? ((kp - 1.f) * (kp - 1.f) + dv * dv) : (kp - dv) * (kp - dv);
  }
  redv[t] = acc;
  __syncthreads();
  for (int s = 128; s; s >>= 1) {
    if (t < s) redv[t] += redv[t + s];
    __syncthreads();
  }
  if (t == 0) out[0] = redv[0];
}

extern "C" void kernel_launch(void* const* d_in, const int* in_sizes, int n_in,
                              void* d_out, int out_size, void* d_ws, size_t ws_size,
                              hipStream_t stream) {
  const unsigned short* x = (const unsigned short*)d_in[0];

  float* kde = (float*)d_ws;                      // NPTS f32
  float* scalf = kde + NPTS;                      // [0] = kdemax
  int* scali = (int*)(scalf + 64);                // [0] = argmin idx
  int* flag = scali + 64;                         // [0] = dtype flag (1=bf16, 0=f32)
  int* order = flag + 64;                         // NPTS (16B-aligned for int4 loads)
  int* rankp = order + NPTS;                      // NPTS
  int* rips = rankp + NPTS;                       // NPTS*KRIPS
  unsigned short* onbr = (unsigned short*)(rips + NPTS * KRIPS);  // NPTS*KRIPS u16
  int* death = (int*)(onbr + NPTS * KRIPS);       // NPTS

  hipLaunchKernelGGL(detect_kernel, dim3(1), dim3(64), 0, stream, x, flag);
  hipLaunchKernelGGL(knn_kernel, dim3(NPTS), dim3(256), 0, stream, x, flag, kde, rips);
  hipLaunchKernelGGL(max_kernel, dim3(1), dim3(256), 0, stream, kde, scalf);
  hipLaunchKernelGGL(norm_kernel, dim3(NPTS / 256), dim3(256), 0, stream, kde, scalf, death);
  hipLaunchKernelGGL(argmin_kernel, dim3(1), dim3(256), 0, stream, kde, scali);
  hipLaunchKernelGGL(sort_kernel, dim3(1), dim3(256), 0, stream, kde, order, rankp);
  hipLaunchKernelGGL(onbr_kernel, dim3(NPTS * KRIPS / 256), dim3(256), 0, stream,
                     order, rankp, rips, onbr);
  hipLaunchKernelGGL(scan_kernel, dim3(1), dim3(64), 0, stream, kde, order, onbr, death, scali);
  hipLaunchKernelGGL(loss_kernel, dim3(1), dim3(256), 0, stream, kde, death, (float*)d_out);
}